// Round 7
// baseline (67.550 us; speedup 1.0000x reference)
//
#include <hip/hip_runtime.h>

constexpr int BATCH = 4096;
constexpr int DIM   = 2048;
constexpr int REPS  = 8;
constexpr float INV2PI = 0.15915494309189535f;  // 1/(2*pi)

constexpr int TPB   = 256;            // 4 waves per block
constexpr int DPW   = 2;              // d's per wave (constants in SGPR)
constexpr int DPB   = 4 * DPW;        // 8 d per block
constexpr int GX    = DIM / DPB;      // 256
constexpr int GY    = 8;              // batch slices
constexpr int SLICE = BATCH / GY;     // 512 rows per block
constexpr int RPL   = SLICE / 64;     // 8 rows per lane
constexpr int NCH   = RPL / 2;        // 4 chunks of 2 rows

__device__ __forceinline__ float rfl(float v) {
    return __int_as_float(__builtin_amdgcn_readfirstlane(__float_as_int(v)));
}

__global__ __launch_bounds__(TPB, 8)
void daruan_kernel(const float* __restrict__ x,       // (BATCH, DIM)
                   const float* __restrict__ theta,   // (DIM, 9, 2)
                   const float* __restrict__ paw,     // (DIM, 8)
                   const float* __restrict__ pab,     // (DIM, 8)
                   const float* __restrict__ postw,   // (DIM)
                   const float* __restrict__ postb,   // (DIM)
                   float* __restrict__ out)           // (BATCH, DIM)
{
    const int lane = threadIdx.x & 63;
    // wave-uniform d index, forced scalar so constant loads become s_load
    const int wid  = __builtin_amdgcn_readfirstlane((int)(threadIdx.x >> 6));
    const int d0   = blockIdx.x * DPB + wid * DPW;

    // ---- per-wave preamble: constants for d0, d0+1 ----
    // Trainable-RZ folding (verified R1-R6): RZ(t0[0])+RY(t1[0]) -> initial
    // Bloch state; RZ(t0[r+1]) (incl. final) absorbed into rep r's bias.
    float s_cy[DPW][REPS], s_sy[DPW][REPS], s_w[DPW][REPS];  // wave-uniform -> SGPR
    float v_b[DPW][REPS];                                     // wave-uniform VGPR
    float Xi[DPW], Yi[DPW], Zi[DPW], pwv[DPW], pbv[DPW];
#pragma unroll
    for (int dd = 0; dd < DPW; ++dd) {
        const int d = d0 + dd;
        const float* th = theta + (size_t)d * 18;   // uniform address -> s_load
        const float t00 = th[0] * INV2PI;
        const float X0  = __builtin_amdgcn_cosf(t00);
        const float Y0  = __builtin_amdgcn_sinf(t00);
        const float t10 = th[1] * INV2PI;
        Xi[dd] = X0 * __builtin_amdgcn_cosf(t10);
        Yi[dd] = Y0;
        Zi[dd] = -X0 * __builtin_amdgcn_sinf(t10);
#pragma unroll
        for (int k = 0; k < REPS; ++k) {
            const float t1 = th[2 * k + 3] * INV2PI;          // theta1[k+1]
            s_cy[dd][k] = rfl(__builtin_amdgcn_cosf(t1));
            s_sy[dd][k] = rfl(__builtin_amdgcn_sinf(t1));
            s_w[dd][k]  = rfl(paw[(size_t)d * REPS + k] * INV2PI);
            v_b[dd][k]  = (pab[(size_t)d * REPS + k] + th[2 * (k + 1)]) * INV2PI;
        }
        pwv[dd] = postw[d];
        pbv[dd] = postb[d];
    }

    // one chain: (row value xv, sub-d dd) -> final Bloch Z
    auto chain = [&](float xv, int dd) -> float {
        // r = 0: state (Xi,Yi,Zi); encoded RZ only (RY folded into init)
        float e  = fmaf(xv, s_w[dd][0], v_b[dd][0]);
        float se = __builtin_amdgcn_sinf(e);
        float ce = __builtin_amdgcn_cosf(e);
        float X = fmaf(Xi[dd], ce, -Yi[dd] * se);
        float Y = fmaf(Xi[dd], se,  Yi[dd] * ce);
        float Z = Zi[dd];
#pragma unroll
        for (int r = 1; r < REPS; ++r) {
            const float cyk = s_cy[dd][r - 1], syk = s_sy[dd][r - 1];
            const float Xb = fmaf(X, cyk,  Z * syk);
            const float Zb = fmaf(Z, cyk, -X * syk);
            e  = fmaf(xv, s_w[dd][r], v_b[dd][r]);
            se = __builtin_amdgcn_sinf(e);
            ce = __builtin_amdgcn_cosf(e);
            X = fmaf(Xb, ce, -Y * se);
            if (r < REPS - 1)                    // Y dead after last rep
                Y = fmaf(Xb, se, Y * ce);
            Z = Zb;
        }
        return fmaf(Z, s_cy[dd][REPS - 1], -X * s_sy[dd][REPS - 1]);  // final RY
    };

    // ---- main loop: lanes span batch rows; float2 covers both d's ----
    const size_t base = (size_t)(blockIdx.y * SLICE + lane) * (DIM / 2) + (d0 >> 1);
    const float2* xp = (const float2*)x + base;
    float2*       op = (float2*)out + base;
    constexpr size_t RSTride = (size_t)64 * (DIM / 2);   // 64 rows in float2 units

    float2 a = xp[0];
    float2 b2 = xp[RSTride];

#pragma unroll 1
    for (int c = 0; c < NCH; ++c) {
        float2 na, nb;
        if (c + 1 < NCH) {                       // prefetch next 2 rows
            na = xp[(size_t)(2 * c + 2) * RSTride];
            nb = xp[(size_t)(2 * c + 3) * RSTride];
        }
        float2 o0, o1;
        o0.x = fmaf(chain(a.x, 0),  pwv[0], pbv[0]);
        o0.y = fmaf(chain(a.y, 1),  pwv[1], pbv[1]);
        o1.x = fmaf(chain(b2.x, 0), pwv[0], pbv[0]);
        o1.y = fmaf(chain(b2.y, 1), pwv[1], pbv[1]);
        op[(size_t)(2 * c)     * RSTride] = o0;
        op[(size_t)(2 * c + 1) * RSTride] = o1;
        a = na; b2 = nb;
    }
}

extern "C" void kernel_launch(void* const* d_in, const int* in_sizes, int n_in,
                              void* d_out, int out_size, void* d_ws, size_t ws_size,
                              hipStream_t stream) {
    const float* x     = (const float*)d_in[0];
    const float* theta = (const float*)d_in[1];
    const float* paw   = (const float*)d_in[2];
    const float* pab   = (const float*)d_in[3];
    const float* postw = (const float*)d_in[4];
    const float* postb = (const float*)d_in[5];
    float* out = (float*)d_out;

    daruan_kernel<<<dim3(GX, GY), dim3(TPB), 0, stream>>>(
        x, theta, paw, pab, postw, postb, out);
}

// Round 8
// 32.294 us; speedup vs baseline: 2.0917x; 2.0917x over previous
//
#include <hip/hip_runtime.h>
#include <math.h>

constexpr int BATCH = 4096;
constexpr int DIM   = 2048;
constexpr int REPS  = 8;
constexpr float INV2PI = 0.15915494309189535f;  // 1/(2*pi)

constexpr int TPB   = 256;
constexpr int GRIDX = DIM / TPB;       // 8
constexpr int GRIDY = 256;             // 2048 blocks
constexpr int BPB   = BATCH / GRIDY;   // 16 rows per block
constexpr int ILP   = 2;               // chains per chunk (keeps sincos arrays cheap)
constexpr int NCH   = BPB / ILP;       // 8 chunks

__global__ __launch_bounds__(TPB, 4)
void daruan_kernel(const float* __restrict__ x,       // (BATCH, DIM)
                   const float* __restrict__ theta,   // (DIM, 9, 2)
                   const float* __restrict__ paw,     // (DIM, 8)
                   const float* __restrict__ pab,     // (DIM, 8)
                   const float* __restrict__ postw,   // (DIM)
                   const float* __restrict__ postb,   // (DIM)
                   float* __restrict__ out)           // (BATCH, DIM)
{
    const int d = blockIdx.x * TPB + threadIdx.x;   // lane-per-d: coalesced

    // ---- per-d preamble (R2-proven). Trainable-RZ folding: RZ(t0[0])+RY(t1[0])
    // -> initial Bloch state; RZ(t0[r+1]) (incl. final) -> rep r's bias.
    const float* th = theta + (size_t)d * 18;
    const float t00 = th[0] * INV2PI;
    const float X0  = __builtin_amdgcn_cosf(t00);
    const float Y0  = __builtin_amdgcn_sinf(t00);
    const float t10 = th[1] * INV2PI;
    const float Xi  = X0 * __builtin_amdgcn_cosf(t10);
    const float Yi  = Y0;
    const float Zi  = -X0 * __builtin_amdgcn_sinf(t10);

    float cy[REPS], sy[REPS], wr[REPS], br[REPS];
#pragma unroll
    for (int k = 0; k < REPS; ++k) {
        const float t1 = th[2 * k + 3] * INV2PI;        // theta1[k+1]
        cy[k] = __builtin_amdgcn_cosf(t1);
        sy[k] = __builtin_amdgcn_sinf(t1);
        wr[k] = paw[(size_t)d * REPS + k] * INV2PI;
        br[k] = (pab[(size_t)d * REPS + k] + th[2 * (k + 1)]) * INV2PI;
    }
    const float pw = postw[d];
    const float pb = postb[d];

    const int bbase = blockIdx.y * BPB;
    const float* xp = x + (size_t)bbase * DIM + d;
    float* op = out + (size_t)bbase * DIM + d;

    auto do_chunk = [&](const float (&xv)[ILP], int cc) {
        // ---- phase A: all angles (state-independent!) ----
        float se[ILP][REPS], ce[ILP][REPS];
#pragma unroll
        for (int i = 0; i < ILP; ++i) {
#pragma unroll
            for (int r = 0; r < REPS; ++r) {
                const float e = fmaf(wr[r], xv[i], br[r]);
                se[i][r] = __builtin_amdgcn_sinf(e);   // 32 trans issued up front,
                ce[i][r] = __builtin_amdgcn_cosf(e);   // decoupled from state chain
            }
        }
        // ---- phase B: pure-fma state chains, no trans dependence ----
#pragma unroll
        for (int i = 0; i < ILP; ++i) {
            float X = fmaf(Xi, ce[i][0], -Yi * se[i][0]);
            float Y = fmaf(Xi, se[i][0],  Yi * ce[i][0]);
            float Z = Zi;
#pragma unroll
            for (int r = 1; r < REPS; ++r) {
                const float Xb = fmaf(X, cy[r - 1],  Z * sy[r - 1]);
                const float Zb = fmaf(Z, cy[r - 1], -X * sy[r - 1]);
                X = fmaf(Xb, ce[i][r], -Y * se[i][r]);
                if (r < REPS - 1)                      // Y dead after last rep
                    Y = fmaf(Xb, se[i][r], Y * ce[i][r]);
                Z = Zb;
            }
            const float Zf = fmaf(Z, cy[REPS - 1], -X * sy[REPS - 1]);
            op[(size_t)(cc * ILP + i) * DIM] = fmaf(Zf, pw, pb);
        }
    };

    float xv[ILP];
#pragma unroll
    for (int i = 0; i < ILP; ++i) xv[i] = xp[(size_t)i * DIM];

#pragma unroll 1
    for (int cc = 0; cc < NCH - 1; ++cc) {
        float xn[ILP];
#pragma unroll
        for (int i = 0; i < ILP; ++i)     // prefetch next chunk's x
            xn[i] = xp[(size_t)((cc + 1) * ILP + i) * DIM];
        do_chunk(xv, cc);
#pragma unroll
        for (int i = 0; i < ILP; ++i) xv[i] = xn[i];
    }
    do_chunk(xv, NCH - 1);
}

extern "C" void kernel_launch(void* const* d_in, const int* in_sizes, int n_in,
                              void* d_out, int out_size, void* d_ws, size_t ws_size,
                              hipStream_t stream) {
    const float* x     = (const float*)d_in[0];
    const float* theta = (const float*)d_in[1];
    const float* paw   = (const float*)d_in[2];
    const float* pab   = (const float*)d_in[3];
    const float* postw = (const float*)d_in[4];
    const float* postb = (const float*)d_in[5];
    float* out = (float*)d_out;

    daruan_kernel<<<dim3(GRIDX, GRIDY), dim3(TPB), 0, stream>>>(
        x, theta, paw, pab, postw, postb, out);
}

// Round 9
// 31.244 us; speedup vs baseline: 2.1620x; 1.0336x over previous
//
#include <hip/hip_runtime.h>
#include <math.h>

constexpr int BATCH = 4096;
constexpr int DIM   = 2048;
constexpr int REPS  = 8;
constexpr float INV2PI = 0.15915494309189535f;  // 1/(2*pi)

constexpr int TPB   = 256;
constexpr int GRIDX = DIM / TPB;       // 8
constexpr int GRIDY = 256;             // 2048 blocks = 8 blocks/CU resident
constexpr int BPB   = BATCH / GRIDY;   // 16 rows per block, 1 row per pipeline stage

__global__ __launch_bounds__(TPB, 4)
void daruan_kernel(const float* __restrict__ x,       // (BATCH, DIM)
                   const float* __restrict__ theta,   // (DIM, 9, 2)
                   const float* __restrict__ paw,     // (DIM, 8)
                   const float* __restrict__ pab,     // (DIM, 8)
                   const float* __restrict__ postw,   // (DIM)
                   const float* __restrict__ postb,   // (DIM)
                   float* __restrict__ out)           // (BATCH, DIM)
{
    const int d = blockIdx.x * TPB + threadIdx.x;   // lane-per-d: coalesced

    // ---- per-d preamble (R2-proven). Trainable-RZ folding: RZ(t0[0])+RY(t1[0])
    // -> initial Bloch state; RZ(t0[r+1]) (incl. final) -> rep r's bias.
    const float* th = theta + (size_t)d * 18;
    const float t00 = th[0] * INV2PI;
    const float X0  = __builtin_amdgcn_cosf(t00);
    const float Y0  = __builtin_amdgcn_sinf(t00);
    const float t10 = th[1] * INV2PI;
    const float Xi  = X0 * __builtin_amdgcn_cosf(t10);
    const float Yi  = Y0;
    const float Zi  = -X0 * __builtin_amdgcn_sinf(t10);

    float cy[REPS], sy[REPS], wr[REPS], br[REPS];
#pragma unroll
    for (int k = 0; k < REPS; ++k) {
        const float t1 = th[2 * k + 3] * INV2PI;        // theta1[k+1]
        cy[k] = __builtin_amdgcn_cosf(t1);
        sy[k] = __builtin_amdgcn_sinf(t1);
        wr[k] = paw[(size_t)d * REPS + k] * INV2PI;
        br[k] = (pab[(size_t)d * REPS + k] + th[2 * (k + 1)]) * INV2PI;
    }
    const float pw = postw[d];
    const float pb = postb[d];

    const int bbase = blockIdx.y * BPB;
    const float* xp = x + (size_t)bbase * DIM + d;
    float* op = out + (size_t)bbase * DIM + d;

    // trans-heavy stage: all 16 sincos for one element (independent stream)
    auto angles = [&](float xv, float (&se)[REPS], float (&ce)[REPS]) {
#pragma unroll
        for (int r = 0; r < REPS; ++r) {
            const float e = fmaf(wr[r], xv, br[r]);
            se[r] = __builtin_amdgcn_sinf(e);
            ce[r] = __builtin_amdgcn_cosf(e);
        }
    };
    // VALU-heavy stage: pure-fma state chain consuming registered sincos
    auto state = [&](const float (&se)[REPS], const float (&ce)[REPS]) -> float {
        float X = fmaf(Xi, ce[0], -Yi * se[0]);
        float Y = fmaf(Xi, se[0],  Yi * ce[0]);
        float Z = Zi;
#pragma unroll
        for (int r = 1; r < REPS; ++r) {
            const float Xb = fmaf(X, cy[r - 1],  Z * sy[r - 1]);
            const float Zb = fmaf(Z, cy[r - 1], -X * sy[r - 1]);
            X = fmaf(Xb, ce[r], -Y * se[r]);
            if (r < REPS - 1)                      // Y dead after last rep
                Y = fmaf(Xb, se[r], Y * ce[r]);
            Z = Zb;
        }
        return fmaf(Z, cy[REPS - 1], -X * sy[REPS - 1]);   // final RY
    };

    // ---- 2-stage software pipeline: trans(c+1) interleaves with state(c) ----
    float seA[REPS], ceA[REPS], seB[REPS], ceB[REPS];
    float x1;
    {
        const float xv0 = xp[0];
        angles(xv0, seA, ceA);
        x1 = xp[DIM];
    }

#pragma unroll 1
    for (int c = 0; c < BPB; c += 2) {
        // stage even: fill B (elem c+1) while consuming A (elem c)
        angles(x1, seB, ceB);
        const float z0 = state(seA, ceA);
        op[(size_t)c * DIM] = fmaf(z0, pw, pb);
        // branch-free next-x loads (index wraps on final iter; row 0 re-read, discarded)
        const float xn0 = xp[(size_t)((c + 2) & (BPB - 1)) * DIM];
        // stage odd: fill A (elem c+2) while consuming B (elem c+1)
        angles(xn0, seA, ceA);
        const float z1 = state(seB, ceB);
        op[(size_t)(c + 1) * DIM] = fmaf(z1, pw, pb);
        x1 = xp[(size_t)((c + 3) & (BPB - 1)) * DIM];
    }
}

extern "C" void kernel_launch(void* const* d_in, const int* in_sizes, int n_in,
                              void* d_out, int out_size, void* d_ws, size_t ws_size,
                              hipStream_t stream) {
    const float* x     = (const float*)d_in[0];
    const float* theta = (const float*)d_in[1];
    const float* paw   = (const float*)d_in[2];
    const float* pab   = (const float*)d_in[3];
    const float* postw = (const float*)d_in[4];
    const float* postb = (const float*)d_in[5];
    float* out = (float*)d_out;

    daruan_kernel<<<dim3(GRIDX, GRIDY), dim3(TPB), 0, stream>>>(
        x, theta, paw, pab, postw, postb, out);
}